// Round 5
// baseline (26.466 us; speedup 1.0000x reference)
//
#include <hip/hip_runtime.h>

#define LENY  1048576
#define NU    (LENY - 1)      // length of u_combined
#define NRBF  11
#define NB    256             // blocks: 1/CU, ample co-residency margin
#define NT    1024            // threads per block (16 waves)
#define NW    (NT / 64)       // waves per block
#define PERT  4               // consecutive elements per thread
#define CHUNK (NT * PERT)     // 4096 elements per block; NB*CHUNK == LENY

typedef float v4f __attribute__((ext_vector_type(4)));

#define L2E 1.44269504088896340736f   // log2(e)

__device__ __forceinline__ float fexp(float x) {
    return __builtin_amdgcn_exp2f(x * L2E);
}
__device__ __forceinline__ float sigmoid10(float x) {
    x = fminf(10.0f, fmaxf(-10.0f, x));
    const float e = __builtin_amdgcn_exp2f(-x * L2E);
    return __builtin_amdgcn_rcpf(1.0f + e);
}

// Relaxed agent-scope atomics: reach the coherence point with NO
// buffer_inv/buffer_wbl2 maintenance (acq/rel poisoned round 2: 62us).
__device__ __forceinline__ void st_relaxed_u64(unsigned long long* p, unsigned long long v) {
    __hip_atomic_store(p, v, __ATOMIC_RELAXED, __HIP_MEMORY_SCOPE_AGENT);
}
__device__ __forceinline__ unsigned long long ld_relaxed_u64(const unsigned long long* p) {
    return __hip_atomic_load(p, __ATOMIC_RELAXED, __HIP_MEMORY_SCOPE_AGENT);
}
__device__ __forceinline__ void st_relaxed_u32(unsigned* p, unsigned v) {
    __hip_atomic_store(p, v, __ATOMIC_RELAXED, __HIP_MEMORY_SCOPE_AGENT);
}
__device__ __forceinline__ unsigned ld_relaxed_u32(const unsigned* p) {
    return __hip_atomic_load(p, __ATOMIC_RELAXED, __HIP_MEMORY_SCOPE_AGENT);
}

__global__ __launch_bounds__(NT, 1) void rbf_fused(
    const float2* __restrict__ yin,
    const float2* __restrict__ xa,
    const float2* __restrict__ xb,
    const float*  __restrict__ rbfw_raw,
    const float*  __restrict__ weights,
    const float*  __restrict__ g1raw,
    const float*  __restrict__ g2raw,
    float2* __restrict__ yout,
    float2* __restrict__ uout,
    double2* __restrict__ bsums,
    unsigned* __restrict__ flags)
{
    const int b = blockIdx.x, t = threadIdx.x;
    const int lane = t & 63, wid = t >> 6;
    const int base = b * CHUNK + t * PERT;   // first owned element

    // ---- uniform params ----
    const float RBFw    = sigmoid10(rbfw_raw[0]);
    const float wdt     = RBFw * 0.2f;               // RBFw*(tmax-tmin)/(NRBF-1)
    const float negInvL = -L2E / (2.0f * wdt * wdt); // folds log2e into RBF exp
    const float g1 = fexp(g1raw[0]);
    const float g2 = fexp(g2raw[0]);
    const float Bf = (float)(1.0 / 60.0);
    const float2 y0 = yin[0];

    float wj[NRBF];
    #pragma unroll
    for (int j = 0; j < NRBF; ++j) wj[j] = weights[j];

    // ---- 16B nontemporal loads (pure streaming, keep caches clean) ----
    const v4f* yp = (const v4f*)yin + (base >> 1);
    const v4f* ap = (const v4f*)xa  + (base >> 1);
    const v4f* bp = (const v4f*)xb  + (base >> 1);
    v4f yv[2], av[2], bv[2];
    #pragma unroll
    for (int q = 0; q < 2; ++q) {
        yv[q] = __builtin_nontemporal_load(yp + q);
        av[q] = __builtin_nontemporal_load(ap + q);
        bv[q] = __builtin_nontemporal_load(bp + q);
    }

    // ---- compute u in registers, per-thread double sums ----
    float ux[PERT], uy[PERT];
    double sx = 0.0, sy = 0.0;
    #pragma unroll
    for (int k = 0; k < PERT; ++k) {
        const int gi = base + k;
        const float ti = ((float)gi - 524287.5f) / 524287.5f;
        float dot = 0.0f;
        #pragma unroll
        for (int j = 0; j < NRBF; ++j) {
            const float c = -1.0f + 0.2f * (float)j;  // linspace(-1,1,11)
            const float d = ti - c;
            dot += __builtin_amdgcn_exp2f(d * d * negInvL) * wj[j];
        }
        const float wt = sigmoid10(dot);

        const float eyx = yv[k >> 1][(k & 1) * 2 + 0];
        const float eyy = yv[k >> 1][(k & 1) * 2 + 1];
        const float eax = av[k >> 1][(k & 1) * 2 + 0];
        const float eay = av[k >> 1][(k & 1) * 2 + 1];
        const float ebx = bv[k >> 1][(k & 1) * 2 + 0];
        const float eby = bv[k >> 1][(k & 1) * 2 + 1];

        const float u1x = -g1 * (eyx - eax);
        const float u1y = -g1 * (eyy - eay);
        const float u2x = -g2 * (eyx - ebx);
        const float u2y = -g2 * (eyy - eby);
        ux[k] = u1x * (1.0f - wt) + u2x * wt;
        uy[k] = u1y * (1.0f - wt) + u2y * wt;
        sx += (double)(ux[k] * Bf);   // phantom last element: only feeds prefixes
        sy += (double)(uy[k] * Bf);   // AFTER the last real y write -> harmless
    }

    // ---- wave shfl_up scan, then wave totals via LDS (1 barrier) ----
    double ix = sx, iy = sy;
    #pragma unroll
    for (int d = 1; d < 64; d <<= 1) {
        const double px = __shfl_up(ix, d, 64);
        const double py = __shfl_up(iy, d, 64);
        if (lane >= d) { ix += px; iy += py; }
    }
    __shared__ double2 wtot[NW];
    if (lane == 63) wtot[wid] = make_double2(ix, iy);
    __syncthreads();
    double wbx = 0.0, wby = 0.0, totx = 0.0, toty = 0.0;
    #pragma unroll
    for (int w = 0; w < NW; ++w) {
        const double vx = wtot[w].x, vy = wtot[w].y;   // uniform addr -> broadcast
        totx += vx; toty += vy;
        if (w < wid) { wbx += vx; wby += vy; }
    }
    const double pex = __shfl_up(ix, 1, 64);
    const double pey = __shfl_up(iy, 1, 64);
    const double myex = (lane == 0) ? wbx : wbx + pex;  // exclusive in-block prefix
    const double myey = (lane == 0) ? wby : wby + pey;

    // ---- publish ASAP: payload -> vmcnt(0) -> flag (all relaxed) ----
    if (t == 0) {
        st_relaxed_u64((unsigned long long*)&bsums[b].x, __builtin_bit_cast(unsigned long long, totx));
        st_relaxed_u64((unsigned long long*)&bsums[b].y, __builtin_bit_cast(unsigned long long, toty));
        asm volatile("s_waitcnt vmcnt(0)" ::: "memory");  // payload at L3 before flag
        st_relaxed_u32(&flags[b], 1u);
    }

    // ---- store u AFTER publish (overlaps the wait), nontemporal ----
    if (base + PERT <= NU) {
        v4f* up = (v4f*)uout + (base >> 1);
        #pragma unroll
        for (int q = 0; q < 2; ++q) {
            v4f r = { ux[2*q], uy[2*q], ux[2*q+1], uy[2*q+1] };
            __builtin_nontemporal_store(r, up + q);
        }
    } else {
        for (int k = 0; k < PERT; ++k)
            if (base + k < NU) uout[base + k] = make_float2(ux[k], uy[k]);
    }

    // ---- lookback: thread t waits on predecessor t (one flag each) ----
    double ox = 0.0, oy = 0.0;
    if (t < b) {
        while (ld_relaxed_u32(&flags[t]) == 0u) __builtin_amdgcn_s_sleep(1);
        asm volatile("" ::: "memory");   // don't hoist payload loads above spin
        ox = __builtin_bit_cast(double, ld_relaxed_u64((const unsigned long long*)&bsums[t].x));
        oy = __builtin_bit_cast(double, ld_relaxed_u64((const unsigned long long*)&bsums[t].y));
    }

    // ---- block-wide reduce of offset partials ----
    #pragma unroll
    for (int d = 32; d > 0; d >>= 1) {
        ox += __shfl_down(ox, d);
        oy += __shfl_down(oy, d);
    }
    __shared__ double2 wred[NW];
    if (lane == 0) wred[wid] = make_double2(ox, oy);
    __syncthreads();
    double offx = 0.0, offy = 0.0;
    #pragma unroll
    for (int w = 0; w < NW; ++w) { offx += wred[w].x; offy += wred[w].y; }

    // ---- exclusive-scan write of y (16B nt stores; y[0]=yin[0] falls out) ----
    double runx = offx + myex;
    double runy = offy + myey;
    const double y0x = (double)y0.x, y0y = (double)y0.y;

    v4f* wyp = (v4f*)yout + (base >> 1);
    #pragma unroll
    for (int q = 0; q < 2; ++q) {
        const int k0 = 2 * q, k1 = 2 * q + 1;
        const float o0x = (float)(y0x + runx);
        const float o0y = (float)(y0y + runy);
        runx += (double)(ux[k0] * Bf);
        runy += (double)(uy[k0] * Bf);
        const float o1x = (float)(y0x + runx);
        const float o1y = (float)(y0y + runy);
        runx += (double)(ux[k1] * Bf);
        runy += (double)(uy[k1] * Bf);
        v4f r = { o0x, o0y, o1x, o1y };
        __builtin_nontemporal_store(r, wyp + q);
    }
}

extern "C" void kernel_launch(void* const* d_in, const int* in_sizes, int n_in,
                              void* d_out, int out_size, void* d_ws, size_t ws_size,
                              hipStream_t stream) {
    const float2* yin  = (const float2*)d_in[0];
    const float2* xa   = (const float2*)d_in[1];
    const float2* xb   = (const float2*)d_in[2];
    const float*  rbfw = (const float*)d_in[3];
    const float*  wts  = (const float*)d_in[4];
    const float*  g1   = (const float*)d_in[5];
    const float*  g2   = (const float*)d_in[6];

    float*  out  = (float*)d_out;
    float2* yout = (float2*)out;                 // y: LENY x 2
    float2* uout = (float2*)(out + 2 * LENY);    // u_combined: (LENY-1) x 2

    double2*  bsums = (double2*)d_ws;                                  // 4 KB
    unsigned* flags = (unsigned*)((char*)d_ws + NB * sizeof(double2)); // 1 KB

    // flags must be 0 at kernel start on every call (graph replays don't
    // re-poison d_ws). Capture-legal: becomes a memset node.
    hipMemsetAsync(flags, 0, NB * sizeof(unsigned), stream);

    rbf_fused<<<NB, NT, 0, stream>>>(yin, xa, xb, rbfw, wts, g1, g2,
                                     yout, uout, bsums, flags);
}

// Round 6
// 18.877 us; speedup vs baseline: 1.4021x; 1.4021x over previous
//
#include <hip/hip_runtime.h>

#define LENY  1048576
#define NU    (LENY - 1)      // length of u_combined
#define NRBF  11
#define NB    2048            // blocks: 8/CU -> 32 waves/CU = full occupancy
#define NT    256             // threads per block (4 waves)
#define NW    (NT / 64)
#define PERT  2               // consecutive elements per thread
#define CHUNK (NT * PERT)     // 512; NB*CHUNK == LENY

typedef float v4f __attribute__((ext_vector_type(4)));

#define L2E 1.44269504088896340736f   // log2(e)

__device__ __forceinline__ float fexp(float x) {
    return __builtin_amdgcn_exp2f(x * L2E);
}
__device__ __forceinline__ float sigmoid10(float x) {
    x = fminf(10.0f, fmaxf(-10.0f, x));
    const float e = __builtin_amdgcn_exp2f(-x * L2E);
    return __builtin_amdgcn_rcpf(1.0f + e);
}

// ---------------- k1: compute u, write it, emit per-block double sums ------
__global__ __launch_bounds__(NT) void rbf_k1(
    const float2* __restrict__ yin,
    const float2* __restrict__ xa,
    const float2* __restrict__ xb,
    const float*  __restrict__ rbfw_raw,
    const float*  __restrict__ weights,
    const float*  __restrict__ g1raw,
    const float*  __restrict__ g2raw,
    float2* __restrict__ uout,
    double2* __restrict__ bsums)
{
    const int b = blockIdx.x, t = threadIdx.x;
    const int lane = t & 63, wid = t >> 6;
    const int base = b * CHUNK + t * PERT;

    const float RBFw    = sigmoid10(rbfw_raw[0]);
    const float wdt     = RBFw * 0.2f;
    const float negInvL = -L2E / (2.0f * wdt * wdt);
    const float g1 = fexp(g1raw[0]);
    const float g2 = fexp(g2raw[0]);
    const float Bf = (float)(1.0 / 60.0);

    float wj[NRBF];
    #pragma unroll
    for (int j = 0; j < NRBF; ++j) wj[j] = weights[j];

    // one float4 per stream = 16B/lane, nontemporal (streamed once)
    const v4f yv = __builtin_nontemporal_load((const v4f*)yin + (base >> 1));
    const v4f av = __builtin_nontemporal_load((const v4f*)xa  + (base >> 1));
    const v4f bv = __builtin_nontemporal_load((const v4f*)xb  + (base >> 1));

    float ux[PERT], uy[PERT];
    double sx = 0.0, sy = 0.0;
    #pragma unroll
    for (int k = 0; k < PERT; ++k) {
        const int gi = base + k;
        const float ti = ((float)gi - 524287.5f) / 524287.5f;
        float dot = 0.0f;
        #pragma unroll
        for (int j = 0; j < NRBF; ++j) {
            const float c = -1.0f + 0.2f * (float)j;
            const float d = ti - c;
            dot += __builtin_amdgcn_exp2f(d * d * negInvL) * wj[j];
        }
        const float wt = sigmoid10(dot);
        const float eyx = yv[2*k], eyy = yv[2*k+1];
        const float eax = av[2*k], eay = av[2*k+1];
        const float ebx = bv[2*k], eby = bv[2*k+1];
        const float u1x = -g1 * (eyx - eax);
        const float u1y = -g1 * (eyy - eay);
        const float u2x = -g2 * (eyx - ebx);
        const float u2y = -g2 * (eyy - eby);
        ux[k] = u1x * (1.0f - wt) + u2x * wt;
        uy[k] = u1y * (1.0f - wt) + u2y * wt;
        sx += (double)(ux[k] * Bf);   // phantom last elem included: its total is
        sy += (double)(uy[k] * Bf);   // never consumed by any prefix that's stored
    }

    // store u CACHED (k2 block b re-reads this exact range -> L2 hit)
    if (base + PERT <= NU) {
        v4f r = { ux[0], uy[0], ux[1], uy[1] };
        *((v4f*)uout + (base >> 1)) = r;
    } else {
        for (int k = 0; k < PERT; ++k)
            if (base + k < NU) uout[base + k] = make_float2(ux[k], uy[k]);
    }

    // block total: wave shfl_down reduce, then 4 wave totals
    #pragma unroll
    for (int d = 32; d > 0; d >>= 1) {
        sx += __shfl_down(sx, d);
        sy += __shfl_down(sy, d);
    }
    __shared__ double2 wtot[NW];
    if (lane == 0) wtot[wid] = make_double2(sx, sy);
    __syncthreads();
    if (t == 0) {
        double tx = 0.0, ty = 0.0;
        #pragma unroll
        for (int w = 0; w < NW; ++w) { tx += wtot[w].x; ty += wtot[w].y; }
        bsums[b] = make_double2(tx, ty);
    }
}

// ---------------- k2: block offset from bsums + in-block scan + y write ----
__global__ __launch_bounds__(NT) void rbf_k2(
    const float2* __restrict__ yin,
    const float2* __restrict__ uin,
    const double2* __restrict__ bsums,
    float2* __restrict__ yout)
{
    const int b = blockIdx.x, t = threadIdx.x;
    const int lane = t & 63, wid = t >> 6;
    const int base = b * CHUNK + t * PERT;
    const float Bf = (float)(1.0 / 60.0);

    // ---- load this thread's u pair (guard only the single OOB tail lane) ----
    float u0x, u0y, u1x, u1y;
    if (base + PERT <= NU) {
        const v4f uv = *((const v4f*)uin + (base >> 1));
        u0x = uv[0]; u0y = uv[1]; u1x = uv[2]; u1y = uv[3];
    } else {
        const float2 z0 = (base < NU) ? uin[base] : make_float2(0.f, 0.f);
        u0x = z0.x; u0y = z0.y; u1x = 0.0f; u1y = 0.0f;
    }

    // ---- block offset: sum bsums[0..b-1], <=8 cached loads per thread ----
    double ox = 0.0, oy = 0.0;
    for (int j = t; j < b; j += NT) { ox += bsums[j].x; oy += bsums[j].y; }
    #pragma unroll
    for (int d = 32; d > 0; d >>= 1) {
        ox += __shfl_down(ox, d);
        oy += __shfl_down(oy, d);
    }
    __shared__ double2 wred[NW];
    if (lane == 0) wred[wid] = make_double2(ox, oy);
    __syncthreads();
    double offx = 0.0, offy = 0.0;
    #pragma unroll
    for (int w = 0; w < NW; ++w) { offx += wred[w].x; offy += wred[w].y; }

    // ---- per-thread sum + wave inclusive scan + block exclusive prefix ----
    const double s0x = (double)(u0x * Bf), s0y = (double)(u0y * Bf);
    const double s1x = (double)(u1x * Bf), s1y = (double)(u1y * Bf);
    const double  sx = s0x + s1x, sy = s0y + s1y;
    double ix = sx, iy = sy;
    #pragma unroll
    for (int d = 1; d < 64; d <<= 1) {
        const double px = __shfl_up(ix, d, 64);
        const double py = __shfl_up(iy, d, 64);
        if (lane >= d) { ix += px; iy += py; }
    }
    __shared__ double2 wtot[NW];
    if (lane == 63) wtot[wid] = make_double2(ix, iy);
    __syncthreads();
    double wbx = 0.0, wby = 0.0;
    #pragma unroll
    for (int w = 0; w < NW; ++w)
        if (w < wid) { wbx += wtot[w].x; wby += wtot[w].y; }
    const double myex = wbx + ix - sx;   // exclusive prefix within block
    const double myey = wby + iy - sy;

    // ---- y write: y[i] = y0 + (offset + exclusive prefix at i) ----
    const float2 y0 = yin[0];
    double runx = offx + myex, runy = offy + myey;
    const double y0x = (double)y0.x, y0y = (double)y0.y;

    const float o0x = (float)(y0x + runx);
    const float o0y = (float)(y0y + runy);
    runx += s0x; runy += s0y;
    const float o1x = (float)(y0x + runx);
    const float o1y = (float)(y0y + runy);
    v4f r = { o0x, o0y, o1x, o1y };
    __builtin_nontemporal_store(r, (v4f*)yout + (base >> 1));
}

extern "C" void kernel_launch(void* const* d_in, const int* in_sizes, int n_in,
                              void* d_out, int out_size, void* d_ws, size_t ws_size,
                              hipStream_t stream) {
    const float2* yin  = (const float2*)d_in[0];
    const float2* xa   = (const float2*)d_in[1];
    const float2* xb   = (const float2*)d_in[2];
    const float*  rbfw = (const float*)d_in[3];
    const float*  wts  = (const float*)d_in[4];
    const float*  g1   = (const float*)d_in[5];
    const float*  g2   = (const float*)d_in[6];

    float*  out  = (float*)d_out;
    float2* yout = (float2*)out;                 // y: LENY x 2
    float2* uout = (float2*)(out + 2 * LENY);    // u_combined: (LENY-1) x 2
    double2* bsums = (double2*)d_ws;             // 2048 * 16 B = 32 KB

    rbf_k1<<<NB, NT, 0, stream>>>(yin, xa, xb, rbfw, wts, g1, g2, uout, bsums);
    rbf_k2<<<NB, NT, 0, stream>>>(yin, uout, bsums, yout);
}